// Round 5
// baseline (144717.627 us; speedup 1.0000x reference)
//
#include <hip/hip_runtime.h>
#include <cstdint>
#include <cstddef>

#define BB 128
#define TT 512
#define VV 512
#define EE 512
#define HH 1024
#define G4H 4096
#define NBLK 256
#define NTHR 512
#define BHS ((size_t)BB * HH)

// ---------- threefry2x32, JAX partitionable scheme. VERIFIED — do not touch. ----------
__device__ __forceinline__ float tf_uniform(unsigned i) {
  unsigned x0 = 0u;
  unsigned x1 = i;
  const unsigned k0 = 0u, k1 = 1u, k2 = 0x1BD11BDBu;
  x0 += k0; x1 += k1;
#define ROTL_(v, r) (((v) << (r)) | ((v) >> (32 - (r))))
#define RND_(r) { x0 += x1; x1 = ROTL_(x1, (r)); x1 ^= x0; }
  RND_(13) RND_(15) RND_(26) RND_(6)   x0 += k1; x1 += k2 + 1u;
  RND_(17) RND_(29) RND_(16) RND_(24)  x0 += k2; x1 += k0 + 2u;
  RND_(13) RND_(15) RND_(26) RND_(6)   x0 += k0; x1 += k1 + 3u;
  RND_(17) RND_(29) RND_(16) RND_(24)  x0 += k1; x1 += k2 + 4u;
  RND_(13) RND_(15) RND_(26) RND_(6)   x0 += k2; x1 += k0 + 5u;
#undef RND_
#undef ROTL_
  unsigned bits = x0 ^ x1;
  unsigned fb = (bits >> 9) | 0x3f800000u;
  return __uint_as_float(fb) - 1.0f;
}

__device__ __forceinline__ float4 ld4(const float* p) { return *(const float4*)(p); }

__global__ __launch_bounds__(256) void init_kernel(float* __restrict__ wsf,
                                                   unsigned* __restrict__ bars) {
  size_t tid = (size_t)blockIdx.x * 256 + threadIdx.x;
  if (tid < 3) bars[tid * 64] = 0u;
  if (tid < 6 * BHS) wsf[tid] = 0.f;
}

// ---------- precompute P0[v][u*4+g] = dot(emb[v], Wih0[g*H+u]) ; P0[0][:] = 0 ----------
__global__ __launch_bounds__(256) void p0_kernel(const float* __restrict__ emb,
                                                 const float* __restrict__ Wih0,
                                                 float* __restrict__ P0) {
  __shared__ float Wsh[16][516];
  const int bn = blockIdx.x;          // units bn*4 .. bn*4+3 -> cols bn*16 .. +15
  const int tid = threadIdx.x;
  for (int i = tid; i < 16 * 128; i += 256) {
    int cc = i >> 7, q = i & 127;
    int ul = cc >> 2, g = cc & 3;
    int grow = g * HH + bn * 4 + ul;
    *(float4*)&Wsh[cc][q * 4] = ld4(Wih0 + (size_t)grow * EE + q * 4);
  }
  __syncthreads();
  const int vv = tid >> 4, cc = tid & 15;
  for (int vb = 0; vb < 32; ++vb) {
    int v = vb * 16 + vv;
    float a0 = 0.f, a1 = 0.f, a2 = 0.f, a3 = 0.f;
    const float* ev = emb + (size_t)v * EE;
    for (int q = 0; q < 128; ++q) {
      float4 x = ld4(ev + q * 4);
      float4 w = *(const float4*)&Wsh[cc][q * 4];
      a0 = fmaf(x.x, w.x, a0); a1 = fmaf(x.y, w.y, a1);
      a2 = fmaf(x.z, w.z, a2); a3 = fmaf(x.w, w.w, a3);
    }
    P0[(size_t)v * G4H + bn * 16 + cc] = (v == 0) ? 0.f : ((a0 + a1) + (a2 + a3));
  }
}

// ============================================================================
// Persistent kernel. 256 blocks x 512 threads (2 waves/SIMD).
// Gates role: rh = bn>>7 (rows rh*64..+63), ct = bn&127 (units ct*8..+7,
//   32 gate-cols interleaved col = ul*4+g). Thread: cg = (lane>>2) owns cols
//   {2cg,2cg+1}; ks = wave*4 + (lane&3) owns k-slice ks*32..+31 (K=1024/part).
// fc role: rt = bn>>4 (rows rt*8..+7), vt = bn&15 (vocab cols vt*32..+31).
// Skewed monotonic counters: cP1, cP2, cfc — only fc's wait is exposed.
// ============================================================================
__global__ __launch_bounds__(NTHR, 2) void lstm_persistent(
    const int* __restrict__ seq,
    const float* __restrict__ teacher_p,
    const float* __restrict__ Whh0,
    const float* __restrict__ bih0, const float* __restrict__ bhh0,
    const float* __restrict__ Wih1, const float* __restrict__ Whh1,
    const float* __restrict__ bih1, const float* __restrict__ bhh1,
    const float* __restrict__ fcw, const float* __restrict__ fcb,
    const float* __restrict__ P0,
    float* __restrict__ out,
    float* __restrict__ h0d, float* __restrict__ c0,
    float* __restrict__ h1d, float* __restrict__ c1,
    unsigned long long* __restrict__ fcpart,
    unsigned* __restrict__ bars) {
  __shared__ float xbuf[9216];          // 8 rows x 32 chunks x 36 (pad) = 36 KB
  __shared__ float scr[8][16][8][2];    // 8 KB
  __shared__ float gaccf[64 * 32];      // 8 KB
  __shared__ int tok_s[BB];

  const int tid  = threadIdx.x;
  const int bn   = blockIdx.x;
  const int wv   = tid >> 6;
  const int lane = tid & 63;
  const int cg   = lane >> 2;           // 0..15
  const int kslo = lane & 3;
  const int ks   = wv * 4 + kslo;       // 0..31
  const int sr   = tid >> 6;            // stage row 0..7
  const int go16 = lane << 4;           // global k offset (floats)
  const int wb   = sr * 1152 + (lane >> 1) * 36 + (lane & 1) * 16;  // LDS write base
  const float* xrd = xbuf + ks * 36;    // LDS read base (imm offsets from here)

  const int r0g  = (bn >> 7) * 64;      // gates rows
  const int u0   = (bn & 127) * 8;      // gates units
  const int rt8  = (bn >> 4) * 8;       // fc rows
  const int vt32 = (bn & 15) * 32;      // fc cols

  unsigned* cP1 = bars;
  unsigned* cP2 = bars + 64;
  unsigned* cfc = bars + 128;

  // persistent cell biases (thread's cell role: r = tid>>3, u = u0 + (tid&7))
  float bc0[4], bc1[4];
  {
    int cu = u0 + (tid & 7);
#pragma unroll
    for (int g = 0; g < 4; ++g) {
      bc0[g] = bih0[g * HH + cu] + bhh0[g * HH + cu];
      bc1[g] = bih1[g * HH + cu] + bhh1[g * HH + cu];
    }
  }
  const float tp = teacher_p[0];

  float4 WA[8], WB[8];   // per-part weight slice (reused/overlaid across parts)

  auto load_w = [&](const float* mat) {
    int c0l = cg * 2, c1l = cg * 2 + 1;
    const float* wp0 = mat + (size_t)((c0l & 3) * HH + u0 + (c0l >> 2)) * HH + ks * 32;
    const float* wp1 = mat + (size_t)((c1l & 3) * HH + u0 + (c1l >> 2)) * HH + ks * 32;
#pragma unroll
    for (int q = 0; q < 8; ++q) { WA[q] = ld4(wp0 + q * 4); WB[q] = ld4(wp1 + q * 4); }
  };

  auto waitc = [&](unsigned* ctr, unsigned tgt) {
    __syncthreads();
    if (tid == 0) {
      int spins = 0;
      while (__hip_atomic_load(ctr, __ATOMIC_RELAXED, __HIP_MEMORY_SCOPE_AGENT) < tgt) {
        __builtin_amdgcn_s_sleep(2);
        if (++spins > 1024) {
          __hip_atomic_fetch_add(ctr, 0u, __ATOMIC_RELAXED, __HIP_MEMORY_SCOPE_AGENT);
          spins = 0;
        }
      }
      __threadfence();   // acquire: invalidate L1/L2 before any thread reads
    }
    __syncthreads();
  };

  auto arrive = [&](unsigned* ctr) {
    __threadfence();     // each thread: drain own stores to coherence point
    __syncthreads();
    if (tid == 0)
      __hip_atomic_fetch_add(ctr, 1u, __ATOMIC_RELAXED, __HIP_MEMORY_SCOPE_AGENT);
  };

  // one K=1024 sub-GEMM over 64 rows (8 tiles of 8 rows), gacc = or += result
  auto gemm_part = [&](const float* src, bool first) {
    const float* gsrc = src + (size_t)(r0g + sr) * HH + go16;
    float4 sg0 = ld4(gsrc), sg1 = ld4(gsrc + 4), sg2 = ld4(gsrc + 8), sg3 = ld4(gsrc + 12);
    for (int bt = 0; bt < 8; ++bt) {
      if (bt && tid < 256) {           // final-reduce of tile bt-1 (reads scr)
        int rr = tid >> 5, c = tid & 31;
        float s = scr[0][c >> 1][rr][c & 1];
#pragma unroll
        for (int w2 = 1; w2 < 8; ++w2) s += scr[w2][c >> 1][rr][c & 1];
        int gi = ((bt - 1) * 8 + rr) * 32 + c;
        if (first) gaccf[gi] = s; else gaccf[gi] += s;
      }
      { float* wp = xbuf + wb;          // stage this tile (xbuf free: prev reads done)
        *(float4*)(wp) = sg0; *(float4*)(wp + 4) = sg1;
        *(float4*)(wp + 8) = sg2; *(float4*)(wp + 12) = sg3; }
      __syncthreads();
      if (bt < 7) { const float* g2 = gsrc + (size_t)(bt + 1) * 8 * HH;
        sg0 = ld4(g2); sg1 = ld4(g2 + 4); sg2 = ld4(g2 + 8); sg3 = ld4(g2 + 12); }
#pragma unroll
      for (int r = 0; r < 8; ++r) {
        const float* xp = xrd + r * 1152;
        float p00 = 0.f, p01 = 0.f, p10 = 0.f, p11 = 0.f;
#pragma unroll
        for (int q = 0; q < 8; ++q) {
          float4 xv = *(const float4*)(xp + (q << 2));
          p00 = fmaf(xv.x, WA[q].x, p00); p01 = fmaf(xv.y, WA[q].y, p01);
          p00 = fmaf(xv.z, WA[q].z, p00); p01 = fmaf(xv.w, WA[q].w, p01);
          p10 = fmaf(xv.x, WB[q].x, p10); p11 = fmaf(xv.y, WB[q].y, p11);
          p10 = fmaf(xv.z, WB[q].z, p10); p11 = fmaf(xv.w, WB[q].w, p11);
        }
        float a0 = p00 + p01, a1 = p10 + p11;
        a0 += __shfl_xor(a0, 1); a0 += __shfl_xor(a0, 2);
        a1 += __shfl_xor(a1, 1); a1 += __shfl_xor(a1, 2);
        if (kslo == 0) { scr[wv][cg][r][0] = a0; scr[wv][cg][r][1] = a1; }
      }
      __syncthreads();
    }
    if (tid < 256) {                    // trailing final-reduce (tile 7)
      int rr = tid >> 5, c = tid & 31;
      float s = scr[0][c >> 1][rr][c & 1];
#pragma unroll
      for (int w2 = 1; w2 < 8; ++w2) s += scr[w2][c >> 1][rr][c & 1];
      int gi = (56 + rr) * 32 + c;
      if (first) gaccf[gi] = s; else gaccf[gi] += s;
    }
    __syncthreads();
  };

  for (int t = 0; t < TT; ++t) {
    const float* h0r = h0d + (size_t)(t & 1) * BHS;
    float*       h0w = h0d + (size_t)((t + 1) & 1) * BHS;
    const float* h1r = h1d + (size_t)(t & 1) * BHS;
    float*       h1w = h1d + (size_t)((t + 1) & 1) * BHS;
    const unsigned tgt0 = (unsigned)t * NBLK, tgt1 = (unsigned)(t + 1) * NBLK;

    // =========== P1: gates0 = Whh0*h0r (GEMM) + P0[tok] (gather) + bias ===========
    load_w(Whh0);
    waitc(cP1, tgt0);                    // h0r ready (usually free)
    gemm_part(h0r, true);
    waitc(cfc, tgt0);                    // fc(t-1) done -> fcpart valid (hidden above)
    {                                    // token select (all 128 rows, deterministic)
      int b = tid >> 2, qd = tid & 3;
      unsigned long long best = 0ull;
      if (t > 0) {
        const unsigned long long* fp = fcpart + b * 16;
#pragma unroll
        for (int i2 = 0; i2 < 4; ++i2) {
          unsigned long long k2 = fp[i2 * 4 + qd];
          if (k2 > best) best = k2;
        }
        unsigned long long o1 = __shfl_xor(best, 1); if (o1 > best) best = o1;
        unsigned long long o2 = __shfl_xor(best, 2); if (o2 > best) best = o2;
      }
      if (qd == 0) {
        int sel;
        if (t == 0) sel = seq[(size_t)b * TT];
        else {
          float uu = tf_uniform((unsigned)(t * BB + b));
          sel = (uu < tp) ? seq[(size_t)b * TT + t]
                          : (int)(0xFFFFFFFFu - (unsigned)(best & 0xFFFFFFFFull));
        }
        tok_s[b] = sel;
      }
    }
    __syncthreads();
    {                                    // fused cell0: thread = (r, u)
      int r = tid >> 3, ul = tid & 7;
      int b = r0g + r, ug = u0 + ul;
      float4 gv = *(const float4*)&gaccf[r * 32 + ul * 4];
      float4 pv = *(const float4*)(P0 + (size_t)tok_s[b] * G4H + ug * 4);
      float gi_ = gv.x + pv.x + bc0[0];
      float gf_ = gv.y + pv.y + bc0[1];
      float gg_ = gv.z + pv.z + bc0[2];
      float go_ = gv.w + pv.w + bc0[3];
      float i_ = 1.f / (1.f + expf(-gi_));
      float f_ = 1.f / (1.f + expf(-gf_));
      float g_ = tanhf(gg_);
      float o_ = 1.f / (1.f + expf(-go_));
      size_t off = (size_t)b * HH + ug;
      float cn = f_ * c0[off] + i_ * g_;
      c0[off] = cn;
      h0w[off] = o_ * tanhf(cn);
    }
    arrive(cP1);

    // =========== P2: gates1 = Whh1*h1r + Wih1*h0w + bias ===========
    load_w(Whh1);
    waitc(cP2, tgt0);                    // h1r ready (free by program order)
    gemm_part(h1r, true);
    load_w(Wih1);                        // issue under the next wait
    waitc(cP1, tgt1);                    // all blocks' h0w ready (hidden by part 1)
    gemm_part(h0w, false);
    {                                    // fused cell1
      int r = tid >> 3, ul = tid & 7;
      int b = r0g + r, ug = u0 + ul;
      float4 gv = *(const float4*)&gaccf[r * 32 + ul * 4];
      float gi_ = gv.x + bc1[0];
      float gf_ = gv.y + bc1[1];
      float gg_ = gv.z + bc1[2];
      float go_ = gv.w + bc1[3];
      float i_ = 1.f / (1.f + expf(-gi_));
      float f_ = 1.f / (1.f + expf(-gf_));
      float g_ = tanhf(gg_);
      float o_ = 1.f / (1.f + expf(-go_));
      size_t off = (size_t)b * HH + ug;
      float cn = f_ * c1[off] + i_ * g_;
      c1[off] = cn;
      h1w[off] = o_ * tanhf(cn);
    }
    arrive(cP2);

    // =========== fc: logits rows rt8..+7 x cols vt32..+31, K=1024 ===========
    {
      int c0l = cg * 2, c1l = cg * 2 + 1;
      const float* fp0 = fcw + (size_t)(vt32 + c0l) * HH + ks * 32;
      const float* fp1 = fcw + (size_t)(vt32 + c1l) * HH + ks * 32;
#pragma unroll
      for (int q = 0; q < 8; ++q) { WA[q] = ld4(fp0 + q * 4); WB[q] = ld4(fp1 + q * 4); }
    }
    waitc(cP2, tgt1);                    // all h1w ready (the one exposed rendezvous)
    {
      const float* gsrc = h1w + (size_t)(rt8 + sr) * HH + go16;
      float4 s0 = ld4(gsrc), s1 = ld4(gsrc + 4), s2 = ld4(gsrc + 8), s3 = ld4(gsrc + 12);
      float* wp = xbuf + wb;
      *(float4*)(wp) = s0; *(float4*)(wp + 4) = s1;
      *(float4*)(wp + 8) = s2; *(float4*)(wp + 12) = s3;
      __syncthreads();
#pragma unroll
      for (int r = 0; r < 8; ++r) {
        const float* xp = xrd + r * 1152;
        float p00 = 0.f, p01 = 0.f, p10 = 0.f, p11 = 0.f;
#pragma unroll
        for (int q = 0; q < 8; ++q) {
          float4 xv = *(const float4*)(xp + (q << 2));
          p00 = fmaf(xv.x, WA[q].x, p00); p01 = fmaf(xv.y, WA[q].y, p01);
          p00 = fmaf(xv.z, WA[q].z, p00); p01 = fmaf(xv.w, WA[q].w, p01);
          p10 = fmaf(xv.x, WB[q].x, p10); p11 = fmaf(xv.y, WB[q].y, p11);
          p10 = fmaf(xv.z, WB[q].z, p10); p11 = fmaf(xv.w, WB[q].w, p11);
        }
        float a0 = p00 + p01, a1 = p10 + p11;
        a0 += __shfl_xor(a0, 1); a0 += __shfl_xor(a0, 2);
        a1 += __shfl_xor(a1, 1); a1 += __shfl_xor(a1, 2);
        if (kslo == 0) { scr[wv][cg][r][0] = a0; scr[wv][cg][r][1] = a1; }
      }
      __syncthreads();
      if (tid < 256) {
        int rr = tid >> 5, c = tid & 31;
        float s = scr[0][c >> 1][rr][c & 1];
#pragma unroll
        for (int w2 = 1; w2 < 8; ++w2) s += scr[w2][c >> 1][rr][c & 1];
        int n = vt32 + c, b = rt8 + rr;
        float lg = s + fcb[n];
        out[((size_t)b * TT + t) * VV + n] = lg;
        unsigned sbits = __float_as_uint(lg);
        sbits = (sbits & 0x80000000u) ? ~sbits : (sbits | 0x80000000u);
        unsigned long long key = ((unsigned long long)sbits << 32) |
                                 (unsigned long long)(0xFFFFFFFFu - (unsigned)n);
#pragma unroll
        for (int m = 1; m <= 16; m <<= 1) {
          unsigned long long o = __shfl_xor(key, m);
          if (o > key) key = o;
        }
        if (c == 0) fcpart[b * 16 + (bn & 15)] = key;
      }
      arrive(cfc);
    }
  }
}

extern "C" void kernel_launch(void* const* d_in, const int* in_sizes, int n_in,
                              void* d_out, int out_size, void* d_ws, size_t ws_size,
                              hipStream_t stream) {
  const int*   seq       = (const int*)d_in[0];
  const float* teacher_p = (const float*)d_in[2];
  const float* embeds    = (const float*)d_in[3];
  const float* W_ih0     = (const float*)d_in[4];
  const float* W_hh0     = (const float*)d_in[5];
  const float* b_ih0     = (const float*)d_in[6];
  const float* b_hh0     = (const float*)d_in[7];
  const float* W_ih1     = (const float*)d_in[8];
  const float* W_hh1     = (const float*)d_in[9];
  const float* b_ih1     = (const float*)d_in[10];
  const float* b_hh1     = (const float*)d_in[11];
  const float* fc_w      = (const float*)d_in[12];
  const float* fc_b      = (const float*)d_in[13];
  float* out = (float*)d_out;

  // ws: h0(2) | c0 | h1(2) | c1 | fcpart(128*16 u64) | bars(3*256B) | P0(8MB)
  char* ws = (char*)d_ws;
  float* h0 = (float*)(ws);
  float* c0 = (float*)(ws + 2 * BHS * 4);
  float* h1 = (float*)(ws + 3 * BHS * 4);
  float* c1 = (float*)(ws + 5 * BHS * 4);
  unsigned long long* fcpart = (unsigned long long*)(ws + 6 * BHS * 4);  // 16 KB
  unsigned* bars = (unsigned*)(ws + 6 * BHS * 4 + 16384);                // 768 B
  float* P0 = (float*)(ws + 6 * BHS * 4 + 16384 + 1024);                 // 8 MB

  init_kernel<<<3072, 256, 0, stream>>>((float*)ws, bars);
  p0_kernel<<<256, 256, 0, stream>>>(embeds, W_ih0, P0);

  void* args[] = {
    (void*)&seq, (void*)&teacher_p,
    (void*)&W_hh0, (void*)&b_ih0, (void*)&b_hh0,
    (void*)&W_ih1, (void*)&W_hh1, (void*)&b_ih1, (void*)&b_hh1,
    (void*)&fc_w, (void*)&fc_b, (void*)&P0, (void*)&out,
    (void*)&h0, (void*)&c0, (void*)&h1, (void*)&c1,
    (void*)&fcpart, (void*)&bars
  };
  hipError_t err = hipLaunchCooperativeKernel((void*)lstm_persistent,
                                              dim3(NBLK), dim3(NTHR), args, 0, stream);
  if (err != hipSuccess) {
    // fallback: plain launch; 256 blocks x 512 thr (54KB LDS, LB(512,2)) are
    // co-resident on 256 CUs; counter scheme remains sound.
    lstm_persistent<<<dim3(NBLK), dim3(NTHR), 0, stream>>>(
        seq, teacher_p, W_hh0, b_ih0, b_hh0, W_ih1, W_hh1, b_ih1, b_hh1,
        fc_w, fc_b, P0, out, h0, c0, h1, c1, fcpart, bars);
  }
}